// Round 2
// baseline (366.951 us; speedup 1.0000x reference)
//
#include <hip/hip_runtime.h>
#include <hip/hip_bf16.h>

// MHA: B=2, S=2048, N_FEAT=1024, H=16, D=64
// Pipeline: f32->bf16 converts; 3 proj GEMMs (bf16 MFMA, fused layout epilogue);
// flash attention (swapped QK^T, lane-local softmax, no barriers); output GEMM.

typedef float f32x4 __attribute__((ext_vector_type(4)));
typedef short bf16x8 __attribute__((ext_vector_type(8)));

typedef const __attribute__((address_space(1))) void* gas_ptr;
typedef __attribute__((address_space(3))) void* las_ptr;

static __device__ __forceinline__ short to_bf16s(float f) {
    __hip_bfloat16 h = __float2bfloat16(f);
    return __builtin_bit_cast(short, h);
}
static __device__ __forceinline__ unsigned pack_bf16(float a, float b) {
    unsigned lo = (unsigned short)__builtin_bit_cast(short, __float2bfloat16(a));
    unsigned hi = (unsigned short)__builtin_bit_cast(short, __float2bfloat16(b));
    return lo | (hi << 16);
}

// ---------------- f32 -> bf16 conversion (vectorized x4) ----------------
__global__ void cvt_kernel(const float* __restrict__ src, short* __restrict__ dst, int n4) {
    int i = blockIdx.x * blockDim.x + threadIdx.x;
    if (i >= n4) return;
    float4 v = reinterpret_cast<const float4*>(src)[i];
    short4 o;
    o.x = to_bf16s(v.x);
    o.y = to_bf16s(v.y);
    o.z = to_bf16s(v.z);
    o.w = to_bf16s(v.w);
    reinterpret_cast<short4*>(dst)[i] = o;
}

// mask (int 0/1) -> additive float bias (0 or -10000, matching reference)
__global__ void maskf_kernel(const int* __restrict__ mask, float* __restrict__ mf) {
    int i = blockIdx.x * 256 + threadIdx.x;
    mf[i] = mask[i] ? -10000.0f : 0.0f;
}

// ---------------- GEMM: C = A @ W^T + bias ----------------
// A: M x K bf16 row-major.  W: N x K bf16 row-major (so both stage identically).
// 128x128 tile, BK=32, 4 waves (2x2), each wave 64x64 via 4x4 16x16x32 MFMA frags.
// EPI: 0 = bf16 out in (B,H,S,64) head-major; 1 = bf16 out in (B,H,64,S) (V^T);
//      2 = f32 out row-major (final output).
template <int EPI>
__global__ __launch_bounds__(256, 2) void gemm_nt(
    const short* __restrict__ A, const short* __restrict__ W,
    const float* __restrict__ bias, void* __restrict__ outp,
    int M, int N, int K)
{
    __shared__ __align__(16) short lds_a[128 * 32];
    __shared__ __align__(16) short lds_b[128 * 32];
    const int tid = threadIdx.x;
    const int w = tid >> 6, l = tid & 63;
    const int lr = l & 15, lh = l >> 4;
    const int m0 = blockIdx.x * 128, n0 = blockIdx.y * 128;
    const int wr = (w >> 1) * 64, wc = (w & 1) * 64;

    f32x4 acc[4][4] = {};

    const int idx0 = tid, idx1 = 256 + tid;
    const int r0 = idx0 >> 2, c0 = (idx0 & 3) * 8;
    const int r1 = idx1 >> 2, c1 = (idx1 & 3) * 8;
    const short* ga0 = A + (long)(m0 + r0) * K + c0;
    const short* ga1 = A + (long)(m0 + r1) * K + c1;
    const short* gb0 = W + (long)(n0 + r0) * K + c0;
    const short* gb1 = W + (long)(n0 + r1) * K + c1;

    for (int k0 = 0; k0 < K; k0 += 32) {
        __builtin_amdgcn_global_load_lds((gas_ptr)(ga0 + k0), (las_ptr)(lds_a + w * 512), 16, 0, 0);
        __builtin_amdgcn_global_load_lds((gas_ptr)(ga1 + k0), (las_ptr)(lds_a + 2048 + w * 512), 16, 0, 0);
        __builtin_amdgcn_global_load_lds((gas_ptr)(gb0 + k0), (las_ptr)(lds_b + w * 512), 16, 0, 0);
        __builtin_amdgcn_global_load_lds((gas_ptr)(gb1 + k0), (las_ptr)(lds_b + 2048 + w * 512), 16, 0, 0);
        __syncthreads();

        bf16x8 af[4], bfr[4];
#pragma unroll
        for (int i = 0; i < 4; ++i)
            af[i] = *reinterpret_cast<const bf16x8*>(lds_a + (wr + i * 16 + lr) * 32 + lh * 8);
#pragma unroll
        for (int i = 0; i < 4; ++i)
            bfr[i] = *reinterpret_cast<const bf16x8*>(lds_b + (wc + i * 16 + lr) * 32 + lh * 8);
#pragma unroll
        for (int i = 0; i < 4; ++i)
#pragma unroll
            for (int j = 0; j < 4; ++j)
                acc[i][j] = __builtin_amdgcn_mfma_f32_16x16x32_bf16(af[i], bfr[j], acc[i][j], 0, 0, 0);
        __syncthreads();
    }

#pragma unroll
    for (int i = 0; i < 4; ++i) {
#pragma unroll
        for (int j = 0; j < 4; ++j) {
#pragma unroll
            for (int r = 0; r < 4; ++r) {
                const int row = m0 + wr + i * 16 + lh * 4 + r;  // M index (b*2048+s)
                const int col = n0 + wc + j * 16 + lr;          // N index (h*64+d)
                float v = acc[i][j][r] + bias[col];
                if constexpr (EPI == 0) {
                    const int b = row >> 11, s = row & 2047;
                    const int h = col >> 6, d = col & 63;
                    ((short*)outp)[(((long)(b * 16 + h)) * 2048 + s) * 64 + d] = to_bf16s(v);
                } else if constexpr (EPI == 1) {
                    const int b = row >> 11, s = row & 2047;
                    const int h = col >> 6, d = col & 63;
                    ((short*)outp)[(((long)(b * 16 + h)) * 64 + d) * 2048 + s] = to_bf16s(v);
                } else {
                    ((float*)outp)[(long)row * N + col] = v;
                }
            }
        }
    }
}

// ---------------- flash attention (swapped QK^T) ----------------
// grid (S/64, B*H), 256 threads (4 waves). Wave w owns 16 q-rows.
// Swapped: sc = mfma(K_rows, Q) -> lane holds scores for q = lane&15,
// k = key0 + (lane>>4)*4 + r  ==> softmax k-reduce is in-register + 2 shfls.
// PV: O^T = mfma(V^T_rows, P^T); P redistributed via per-wave LDS (no barriers).

struct KV {
    bf16x8 k0lo, k0hi, k1lo, k1hi;  // two 16-key tiles, d 0-31 / 32-63
    bf16x8 v0, v1, v2, v3;          // V^T rows for d-tiles 0..3
    f32x4 mb0, mb1;                 // mask bias for the two key tiles
};

static __device__ __forceinline__ void kv_load(KV& f, const short* Kbase, const short* Vbase,
                                               const float* mfp, int key0) {
    const short* Kp0 = Kbase + key0 * 64;
    f.k0lo = *reinterpret_cast<const bf16x8*>(Kp0);
    f.k0hi = *reinterpret_cast<const bf16x8*>(Kp0 + 32);
    const short* Kp1 = Kp0 + 16 * 64;
    f.k1lo = *reinterpret_cast<const bf16x8*>(Kp1);
    f.k1hi = *reinterpret_cast<const bf16x8*>(Kp1 + 32);
    const short* Vp = Vbase + key0;
    f.v0 = *reinterpret_cast<const bf16x8*>(Vp);
    f.v1 = *reinterpret_cast<const bf16x8*>(Vp + 16 * 2048);
    f.v2 = *reinterpret_cast<const bf16x8*>(Vp + 32 * 2048);
    f.v3 = *reinterpret_cast<const bf16x8*>(Vp + 48 * 2048);
    f.mb0 = *reinterpret_cast<const f32x4*>(mfp + key0);
    f.mb1 = *reinterpret_cast<const f32x4*>(mfp + key0 + 16);
}

static __device__ __forceinline__ void kv_step(const KV& f, bf16x8 qf0, bf16x8 qf1,
                                               short* pbuf, int lr, int lh,
                                               float& m, float& ls, f32x4 ao[4]) {
    f32x4 sc0 = {}, sc1 = {};
    sc0 = __builtin_amdgcn_mfma_f32_16x16x32_bf16(f.k0lo, qf0, sc0, 0, 0, 0);
    sc0 = __builtin_amdgcn_mfma_f32_16x16x32_bf16(f.k0hi, qf1, sc0, 0, 0, 0);
    sc1 = __builtin_amdgcn_mfma_f32_16x16x32_bf16(f.k1lo, qf0, sc1, 0, 0, 0);
    sc1 = __builtin_amdgcn_mfma_f32_16x16x32_bf16(f.k1hi, qf1, sc1, 0, 0, 0);

    float s0[4], s1[4];
#pragma unroll
    for (int r = 0; r < 4; ++r) {
        s0[r] = sc0[r] * 0.125f + f.mb0[r];
        s1[r] = sc1[r] * 0.125f + f.mb1[r];
    }
    float t = fmaxf(fmaxf(fmaxf(s0[0], s0[1]), fmaxf(s0[2], s0[3])),
                    fmaxf(fmaxf(s1[0], s1[1]), fmaxf(s1[2], s1[3])));
    t = fmaxf(t, __shfl_xor(t, 16));
    t = fmaxf(t, __shfl_xor(t, 32));
    const float mn = fmaxf(m, t);
    const float sf = __expf(m - mn);
    float p0[4], p1[4], ps = 0.f;
#pragma unroll
    for (int r = 0; r < 4; ++r) {
        p0[r] = __expf(s0[r] - mn); ps += p0[r];
        p1[r] = __expf(s1[r] - mn); ps += p1[r];
    }
    ps += __shfl_xor(ps, 16);
    ps += __shfl_xor(ps, 32);
    ls = ls * sf + ps;
    m = mn;
#pragma unroll
    for (int dt = 0; dt < 4; ++dt) ao[dt] *= sf;

    // P^T (lane: q=lr, k=4*lh+r / 16+4*lh+r) -> LDS row-major P[q][k], stride 40 shorts.
    // Per-wave buffer: no barrier; compiler lgkmcnt orders write->read.
    unsigned* prw = reinterpret_cast<unsigned*>(pbuf + lr * 40);
    prw[lh * 2]     = pack_bf16(p0[0], p0[1]);
    prw[lh * 2 + 1] = pack_bf16(p0[2], p0[3]);
    unsigned* prw1 = reinterpret_cast<unsigned*>(pbuf + lr * 40 + 16);
    prw1[lh * 2]     = pack_bf16(p1[0], p1[1]);
    prw1[lh * 2 + 1] = pack_bf16(p1[2], p1[3]);
    const bf16x8 pb = *reinterpret_cast<const bf16x8*>(pbuf + lr * 40 + lh * 8);

    ao[0] = __builtin_amdgcn_mfma_f32_16x16x32_bf16(f.v0, pb, ao[0], 0, 0, 0);
    ao[1] = __builtin_amdgcn_mfma_f32_16x16x32_bf16(f.v1, pb, ao[1], 0, 0, 0);
    ao[2] = __builtin_amdgcn_mfma_f32_16x16x32_bf16(f.v2, pb, ao[2], 0, 0, 0);
    ao[3] = __builtin_amdgcn_mfma_f32_16x16x32_bf16(f.v3, pb, ao[3], 0, 0, 0);
}

__global__ __launch_bounds__(256, 2) void attn_kernel(
    const short* __restrict__ Q, const short* __restrict__ Kmat,
    const short* __restrict__ Vt, const float* __restrict__ maskf,
    short* __restrict__ X)
{
    __shared__ __align__(16) short lds_p[4][2][16 * 40];
    const int bh = blockIdx.y;
    const int b = bh >> 4, h = bh & 15;
    const int q0 = blockIdx.x * 64;
    const int w = threadIdx.x >> 6, l = threadIdx.x & 63;
    const int lr = l & 15, lh = l >> 4;

    // Q B-frag: lane holds Q[q0 + w*16 + lr][d = lh*8 + i]
    const short* Qp = Q + ((long)bh * 2048 + q0 + w * 16 + lr) * 64 + lh * 8;
    const bf16x8 qf0 = *reinterpret_cast<const bf16x8*>(Qp);
    const bf16x8 qf1 = *reinterpret_cast<const bf16x8*>(Qp + 32);

    const short* Kbase = Kmat + (long)bh * 2048 * 64 + (long)lr * 64 + lh * 8;
    const short* Vbase = Vt + ((long)bh * 64 + lr) * 2048 + lh * 8;
    const float* mfp = maskf + b * 2048 + lh * 4;

    f32x4 ao[4] = {};
    float m = -1e30f, ls = 0.f;

    KV fA, fB;
    kv_load(fA, Kbase, Vbase, mfp, 0);
    for (int t = 0; t < 32; ++t) {
        const int key0 = t * 64;
        kv_load(fB, Kbase, Vbase, mfp, key0 + 32);
        kv_step(fA, qf0, qf1, &lds_p[w][0][0], lr, lh, m, ls, ao);
        if (t < 31) kv_load(fA, Kbase, Vbase, mfp, key0 + 64);
        kv_step(fB, qf0, qf1, &lds_p[w][1][0], lr, lh, m, ls, ao);
    }

    // lane holds O^T[d = dt*16 + lh*4 + r][q = lr]
    const float inv = 1.0f / fmaxf(ls, 1e-30f);
    const int s = q0 + w * 16 + lr;
    short* Xp = X + ((long)b * 2048 + s) * 1024 + h * 64 + lh * 4;
#pragma unroll
    for (int dt = 0; dt < 4; ++dt) {
        short4 o;
        o.x = to_bf16s(ao[dt][0] * inv);
        o.y = to_bf16s(ao[dt][1] * inv);
        o.z = to_bf16s(ao[dt][2] * inv);
        o.w = to_bf16s(ao[dt][3] * inv);
        *reinterpret_cast<short4*>(Xp + dt * 16) = o;
    }
}

// ---------------- launch ----------------
extern "C" void kernel_launch(void* const* d_in, const int* in_sizes, int n_in,
                              void* d_out, int out_size, void* d_ws, size_t ws_size,
                              hipStream_t stream) {
    const float* query = (const float*)d_in[0];
    const float* key_  = (const float*)d_in[1];
    const float* value = (const float*)d_in[2];
    const int*   mask  = (const int*)d_in[3];
    const float* w_q = (const float*)d_in[4];
    const float* b_q = (const float*)d_in[5];
    const float* w_k = (const float*)d_in[6];
    const float* b_k = (const float*)d_in[7];
    const float* w_v = (const float*)d_in[8];
    const float* b_v = (const float*)d_in[9];
    const float* w_o = (const float*)d_in[10];
    const float* b_o = (const float*)d_in[11];

    const long SEQ = 4194304;  // 4096*1024 elements
    const long WSZ = 1048576;  // 1024*1024
    short* ws = (short*)d_ws;
    short* cq = ws;            // converted query
    short* ck = cq + SEQ;
    short* cv = ck + SEQ;
    short* wq = cv + SEQ;
    short* wk = wq + WSZ;
    short* wv = wk + WSZ;
    short* wo = wv + WSZ;
    short* Qb = wo + WSZ;      // (B,H,S,64)
    short* Kb = Qb + SEQ;
    short* Vt = Kb + SEQ;      // (B,H,64,S)
    short* Xb = cq;            // reuse: cq dead after Q-projection
    float* mkf = (float*)cv;   // reuse: cv dead after V-projection (launched after)

    cvt_kernel<<<4096, 256, 0, stream>>>(query, cq, 1048576);
    cvt_kernel<<<4096, 256, 0, stream>>>(key_, ck, 1048576);
    cvt_kernel<<<4096, 256, 0, stream>>>(value, cv, 1048576);
    cvt_kernel<<<1024, 256, 0, stream>>>(w_q, wq, 262144);
    cvt_kernel<<<1024, 256, 0, stream>>>(w_k, wk, 262144);
    cvt_kernel<<<1024, 256, 0, stream>>>(w_v, wv, 262144);
    cvt_kernel<<<1024, 256, 0, stream>>>(w_o, wo, 262144);

    dim3 blk(256);
    dim3 gP(32, 8);  // M=4096 / 128, N=1024 / 128
    gemm_nt<0><<<gP, blk, 0, stream>>>(cq, wq, b_q, Qb, 4096, 1024, 1024);
    gemm_nt<0><<<gP, blk, 0, stream>>>(ck, wk, b_k, Kb, 4096, 1024, 1024);
    gemm_nt<1><<<gP, blk, 0, stream>>>(cv, wv, b_v, Vt, 4096, 1024, 1024);

    maskf_kernel<<<16, 256, 0, stream>>>(mask, mkf);  // after V GEMM (cv reuse)

    attn_kernel<<<dim3(32, 32), blk, 0, stream>>>(Qb, Kb, Vt, mkf, Xb);

    gemm_nt<2><<<gP, blk, 0, stream>>>(Xb, wo, b_o, d_out, 4096, 1024, 1024);
}